// Round 7
// baseline (328.492 us; speedup 1.0000x reference)
//
#include <hip/hip_runtime.h>
#include <hip/hip_fp16.h>

// ---------------------------------------------------------------------------
// 3-layer GCN + linear head.  N=50000, E=800000, D=128.
// v7 = v3 structure (best: 277.9us) with:
//  * 4-way BANKED edge counters (separate 64B lines): atomic chain depth
//    16 -> 4.  Bank = e&3; u64 atomic packs (count<<32 | q15 wsum).
//  * k_fill compacts slots: final = prefix(counts of banks<bank) + locInBank
//    (prefix from the 4 header words it reads anyway for dinv) -> agg sees
//    a fully compact CSR row, identical to v3.
//  * k_dinv gone: fill computes dinv inline; agg sums 4 header words +
//    rsqrt in epoch-0, in parallel with UNCONDITIONAL first-window ev loads.
// 9 dispatches: memset, build, fill, (agg,gemm)x3.
// [v2: agg is LATENCY-bound, keep 16B/lane gathers + MLP.  v4: agg+gemm
//  fusion costs occupancy/balance.  v5: batching atomics per thread hurts.
//  v6: scattered ev writes in build hurt; per-edge dinv gathers in agg hurt.]
// ---------------------------------------------------------------------------

#define D 128
#define SLOTS 64          // fixed CSR capacity per node (P(deg>=64) ~ 1e-13)
#define NBANK 4

typedef __attribute__((ext_vector_type(8))) _Float16 half8;
typedef __attribute__((ext_vector_type(4))) float floatx4;

// ---- MFMA GEMM body: C = A @ W (+bias), fp16 in/out, fp32 accum ----------
// 128 rows/block, 8 waves x 16 rows, v_mfma_f32_16x16x32_f16.
template <bool A_IS_F32>
__device__ __forceinline__ void gemm_body(int bid, const void* Aptr,
                                          const float* W, const float* bias,
                                          float* C32, __half* C16, int N) {
    __shared__ _Float16 Wl[128][136];
    int tid = threadIdx.x;

#pragma unroll
    for (int j = 0; j < 32; j++) {
        int e = tid + j * 512;          // 16384 elements
        Wl[e & 127][e >> 7] = (_Float16)W[e];
    }
    __syncthreads();

    int wave = tid >> 6, lane = tid & 63;
    int m = lane & 15, q = lane >> 4;
    int R0 = bid * 128 + wave * 16;

    const float*  A32p = (const float*)Aptr;
    const __half* A16p = (const __half*)Aptr;

    floatx4 acc[8];
#pragma unroll
    for (int ct = 0; ct < 8; ct++) acc[ct] = (floatx4){0.f, 0.f, 0.f, 0.f};

    int arow = R0 + m;
    bool rok = arow < N;

#pragma unroll
    for (int kk = 0; kk < 4; kk++) {
        half8 a = {0, 0, 0, 0, 0, 0, 0, 0};
        if (rok) {
            if (A_IS_F32) {
                const float* p = &A32p[(size_t)arow * 128 + kk * 32 + q * 8];
                float4 f0 = *(const float4*)p;
                float4 f1 = *(const float4*)(p + 4);
                a[0] = (_Float16)f0.x; a[1] = (_Float16)f0.y;
                a[2] = (_Float16)f0.z; a[3] = (_Float16)f0.w;
                a[4] = (_Float16)f1.x; a[5] = (_Float16)f1.y;
                a[6] = (_Float16)f1.z; a[7] = (_Float16)f1.w;
            } else {
                a = *(const half8*)&A16p[(size_t)arow * 128 + kk * 32 + q * 8];
            }
        }
#pragma unroll
        for (int ct = 0; ct < 8; ct++) {
            half8 b = *(const half8*)&Wl[ct * 16 + m][kk * 32 + q * 8];
            acc[ct] = __builtin_amdgcn_mfma_f32_16x16x32_f16(a, b, acc[ct], 0, 0, 0);
        }
    }

#pragma unroll
    for (int r = 0; r < 4; r++) {
        int row = R0 + q * 4 + r;
        if (row >= N) continue;
#pragma unroll
        for (int ct = 0; ct < 8; ct++) {
            int col = ct * 16 + m;
            float v = acc[ct][r];
            if (C16) C16[(size_t)row * 128 + col] = __float2half_rn(v);
            if (C32) C32[(size_t)row * 128 + col] = v + bias[col];
        }
    }
}

template <bool A_IS_F32>
__global__ __launch_bounds__(512) void k_gemm_mfma(const void* __restrict__ Aptr,
                                                   const float* __restrict__ W,
                                                   const float* __restrict__ bias,
                                                   float* __restrict__ C32,
                                                   __half* __restrict__ C16, int N) {
    gemm_body<A_IS_F32>(blockIdx.x, Aptr, W, bias, C32, C16, N);
}

// ---- fused: blocks [0,gg) = GEMM1 (x@W1 -> y16); [gg,..) = edge atomics ---
// Edge pass: 1 edge/thread; bank = e&3 -> u64 atomic on line (d*4+bank).
__global__ __launch_bounds__(512) void k_build_gemm1(const float* __restrict__ x,
                                                     const float* __restrict__ W1,
                                                     __half* __restrict__ y16,
                                                     const int* __restrict__ dst,
                                                     const float* __restrict__ w,
                                                     unsigned long long* __restrict__ cntb,
                                                     int* __restrict__ loc,
                                                     int N, int E, int gg) {
    int b = (int)blockIdx.x;
    if (b < gg) {
        gemm_body<true>(b, x, W1, nullptr, nullptr, y16, N);
        return;
    }
    int e = (b - gg) * 512 + threadIdx.x;
    if (e < E) {
        int d = dst[e];
        int bank = e & (NBANK - 1);
        unsigned int wq = __float2uint_rn(w[e] * 32767.0f);
        unsigned long long old =
            atomicAdd(&cntb[((size_t)d * NBANK + bank) * 8],
                      (1ull << 32) | (unsigned long long)wq);
        loc[e] = (int)(old >> 32);
    }
}

// ---- CSR fill (compacting): ev[d*64 + prefix+loc] = (q15(norm)<<17)|src ---
// dinv for s and d computed inline from banked wsums (4 u64 words each).
__global__ __launch_bounds__(256) void k_fill(const int* __restrict__ ei,
                                              const float* __restrict__ w,
                                              const unsigned long long* __restrict__ cntb,
                                              const int* __restrict__ loc,
                                              unsigned int* __restrict__ ev, int E) {
    int e = blockIdx.x * 256 + threadIdx.x;
    if (e < E) {
        int s = ei[e];
        int d = ei[E + e];
        int bank = e & (NBANK - 1);

        unsigned long long s0 = cntb[((size_t)s * NBANK + 0) * 8];
        unsigned long long s1 = cntb[((size_t)s * NBANK + 1) * 8];
        unsigned long long s2 = cntb[((size_t)s * NBANK + 2) * 8];
        unsigned long long s3 = cntb[((size_t)s * NBANK + 3) * 8];
        unsigned long long d0 = cntb[((size_t)d * NBANK + 0) * 8];
        unsigned long long d1 = cntb[((size_t)d * NBANK + 1) * 8];
        unsigned long long d2 = cntb[((size_t)d * NBANK + 2) * 8];
        unsigned long long d3 = cntb[((size_t)d * NBANK + 3) * 8];

        unsigned int ws = (unsigned int)s0 + (unsigned int)s1 +
                          (unsigned int)s2 + (unsigned int)s3;
        unsigned int wd = (unsigned int)d0 + (unsigned int)d1 +
                          (unsigned int)d2 + (unsigned int)d3;
        float dvs = rsqrtf(1.0f + (float)ws * (1.0f / 32767.0f));
        float dvd = rsqrtf(1.0f + (float)wd * (1.0f / 32767.0f));

        int c0 = (int)(d0 >> 32), c1 = (int)(d1 >> 32), c2 = (int)(d2 >> 32);
        int prefix = (bank > 0 ? c0 : 0) + (bank > 1 ? c1 : 0) + (bank > 2 ? c2 : 0);
        int fin = prefix + loc[e];

        float val = w[e] * dvs * dvd;   // in [0,1)
        unsigned int wq = __float2uint_rn(val * 32767.0f);
        if (fin < SLOTS)
            ev[(size_t)d * SLOTS + fin] = (wq << 17) | (unsigned int)s;
    }
}

// ---- aggregation: out_i = b + dinv_i^2*y_i + sum val*y_src ---------------
// One wave per node; quarter-wave per slot; lane sl covers feats sl*8..+7.
// Epoch 0: 4 header words + first-window ev[0..15] all in flight.
// Window0: 4 gathers in flight (addr clamped; weight 0 when predicated off).
// Tail (cnt>16): 32-slot windows, 8 gathers in flight.
__device__ __forceinline__ void fma8(float acc[8], float v, uint4 q) {
    union { uint4 uu; __half2 h2[4]; } U; U.uu = q;
    float2 f0 = __half22float2(U.h2[0]);
    float2 f1 = __half22float2(U.h2[1]);
    float2 f2 = __half22float2(U.h2[2]);
    float2 f3 = __half22float2(U.h2[3]);
    acc[0] = fmaf(v, f0.x, acc[0]); acc[1] = fmaf(v, f0.y, acc[1]);
    acc[2] = fmaf(v, f1.x, acc[2]); acc[3] = fmaf(v, f1.y, acc[3]);
    acc[4] = fmaf(v, f2.x, acc[4]); acc[5] = fmaf(v, f2.y, acc[5]);
    acc[6] = fmaf(v, f3.x, acc[6]); acc[7] = fmaf(v, f3.y, acc[7]);
}

__global__ __launch_bounds__(256) void k_agg(const __half* __restrict__ y16,
                                             const unsigned long long* __restrict__ cntb,
                                             const unsigned int* __restrict__ ev,
                                             const float* __restrict__ bias,
                                             __half* __restrict__ out16,
                                             int N, int relu) {
    int i = blockIdx.x * 4 + (threadIdx.x >> 6);
    if (i >= N) return;
    int lane = threadIdx.x & 63;
    int g = lane >> 4;
    int sl = lane & 15;

    const unsigned int* evp = ev + (size_t)i * SLOTS;

    // ---- epoch 0: header words + first-window ev, all independent --------
    unsigned long long h0 = cntb[((size_t)i * NBANK + 0) * 8];
    unsigned long long h1 = cntb[((size_t)i * NBANK + 1) * 8];
    unsigned long long h2 = cntb[((size_t)i * NBANK + 2) * 8];
    unsigned long long h3 = cntb[((size_t)i * NBANK + 3) * 8];
    unsigned int p0[4];
#pragma unroll
    for (int u = 0; u < 4; u++) p0[u] = evp[u * 4 + g];   // slots 0..15

    int cnt = (int)((h0 >> 32) + (h1 >> 32) + (h2 >> 32) + (h3 >> 32));
    cnt = min(cnt, SLOTS);
    unsigned int wsum = (unsigned int)h0 + (unsigned int)h1 +
                        (unsigned int)h2 + (unsigned int)h3;
    float di = rsqrtf(1.0f + (float)wsum * (1.0f / 32767.0f));

    float acc[8];
#pragma unroll
    for (int j = 0; j < 8; j++) acc[j] = 0.f;

    // ---- window 0 (slots 0..15) ------------------------------------------
    {
        float v[4]; uint4 q4[4];
#pragma unroll
        for (int u = 0; u < 4; u++) {
            bool ok = (u * 4 + g) < cnt;
            v[u] = ok ? (float)(p0[u] >> 17) * (1.0f / 32767.0f) : 0.0f;
            int s = min((int)(p0[u] & 0x1FFFFu), N - 1);  // clamp: slot may be garbage
            q4[u] = *(const uint4*)&y16[(size_t)s * D + sl * 8];
        }
#pragma unroll
        for (int u = 0; u < 4; u++) fma8(acc, v[u], q4[u]);
    }

    // ---- tail windows (32 slots, 8 gathers/lane) -------------------------
    for (int base = 16; base < cnt; base += 32) {
        unsigned int p[8]; float v[8]; uint4 q4[8];
#pragma unroll
        for (int u = 0; u < 8; u++) {
            int idx = base + u * 4 + g;
            bool ok = idx < cnt;
            p[u] = evp[ok ? idx : 0];   // slot 0 valid (cnt>16 here)
            v[u] = ok ? (float)(p[u] >> 17) * (1.0f / 32767.0f) : 0.0f;
        }
#pragma unroll
        for (int u = 0; u < 8; u++)
            q4[u] = *(const uint4*)&y16[(size_t)(p[u] & 0x1FFFFu) * D + sl * 8];
#pragma unroll
        for (int u = 0; u < 8; u++) fma8(acc, v[u], q4[u]);
    }

    // fold the 4 quarter-wave partials (lane ^16, ^32)
#pragma unroll
    for (int j = 0; j < 8; j++) {
        acc[j] += __shfl_xor(acc[j], 16, 64);
        acc[j] += __shfl_xor(acc[j], 32, 64);
    }

    if (g == 0) {
        float di2 = di * di;
        union { uint4 u; __half2 h2[4]; } S;
        S.u = *(const uint4*)&y16[(size_t)i * D + sl * 8];
        float2 s0 = __half22float2(S.h2[0]);
        float2 s1 = __half22float2(S.h2[1]);
        float2 s2 = __half22float2(S.h2[2]);
        float2 s3 = __half22float2(S.h2[3]);
        float4 b0 = *(const float4*)&bias[sl * 8];
        float4 b1 = *(const float4*)&bias[sl * 8 + 4];
        float o[8];
        o[0] = b0.x + acc[0] + di2 * s0.x;
        o[1] = b0.y + acc[1] + di2 * s0.y;
        o[2] = b0.z + acc[2] + di2 * s1.x;
        o[3] = b0.w + acc[3] + di2 * s1.y;
        o[4] = b1.x + acc[4] + di2 * s2.x;
        o[5] = b1.y + acc[5] + di2 * s2.y;
        o[6] = b1.z + acc[6] + di2 * s3.x;
        o[7] = b1.w + acc[7] + di2 * s3.y;
        if (relu) {
#pragma unroll
            for (int j = 0; j < 8; j++) o[j] = fmaxf(o[j], 0.f);
        }
        union { uint4 u; __half2 h2[4]; } O;
        O.h2[0] = __float22half2_rn(make_float2(o[0], o[1]));
        O.h2[1] = __float22half2_rn(make_float2(o[2], o[3]));
        O.h2[2] = __float22half2_rn(make_float2(o[4], o[5]));
        O.h2[3] = __float22half2_rn(make_float2(o[6], o[7]));
        *(uint4*)&out16[(size_t)i * D + sl * 8] = O.u;
    }
}

// ---------------------------------------------------------------------------
extern "C" void kernel_launch(void* const* d_in, const int* in_sizes, int n_in,
                              void* d_out, int out_size, void* d_ws, size_t ws_size,
                              hipStream_t stream) {
    const float* x  = (const float*)d_in[0];
    const int*   ei = (const int*)d_in[1];     // [2,E]: src row then dst row
    const float* ew = (const float*)d_in[2];
    const float* W1 = (const float*)d_in[3];
    const float* b1 = (const float*)d_in[4];
    const float* W2 = (const float*)d_in[5];
    const float* b2 = (const float*)d_in[6];
    const float* W3 = (const float*)d_in[7];
    const float* b3 = (const float*)d_in[8];
    const float* Wl = (const float*)d_in[9];
    const float* bl = (const float*)d_in[10];

    int N = in_sizes[0] / D;    // 50000
    int E = in_sizes[2];        // 800000

    char* ws = (char*)d_ws;
    size_t off = 0;
    auto alloc = [&](size_t bytes) {
        void* p = ws + off;
        off = (off + bytes + 255) & ~(size_t)255;
        return p;
    };
    unsigned long long* cntb = (unsigned long long*)alloc((size_t)N * NBANK * 64);
    int*    loc  = (int*)alloc((size_t)E * 4);
    unsigned int* ev = (unsigned int*)alloc((size_t)N * SLOTS * 4);  // 12.8MB
    __half* yA   = (__half*)alloc((size_t)N * D * 2);   // row-major [N][128]
    __half* yB   = (__half*)alloc((size_t)N * D * 2);   // row-major [N][128]

    int nbE    = (E + 255) / 256;      // 3125 (fill)
    int nbE512 = (E + 511) / 512;      // 1563 (build edge part)
    int gg     = (N + 127) / 128;      // 391 GEMM blocks
    int ga     = (N + 3) / 4;          // 12500 agg blocks (4 waves each)

    hipMemsetAsync(cntb, 0, (size_t)N * NBANK * 64, stream);
    k_build_gemm1<<<gg + nbE512, 512, 0, stream>>>(x, W1, yA, ei + E, ew,
                                                   cntb, loc, N, E, gg);
    k_fill<<<nbE, 256, 0, stream>>>(ei, ew, cntb, loc, ev, E);

    k_agg<<<ga, 256, 0, stream>>>(yA, cntb, ev, b1, yB, N, 1);
    k_gemm_mfma<false><<<gg, 512, 0, stream>>>(yB, W2, nullptr, nullptr, yA, N);
    k_agg<<<ga, 256, 0, stream>>>(yA, cntb, ev, b2, yB, N, 1);
    k_gemm_mfma<false><<<gg, 512, 0, stream>>>(yB, W3, nullptr, nullptr, yA, N);
    k_agg<<<ga, 256, 0, stream>>>(yA, cntb, ev, b3, yB, N, 0);
    k_gemm_mfma<false><<<gg, 512, 0, stream>>>(yB, Wl, bl, (float*)d_out, nullptr, N);
}

// Round 8
// 277.584 us; speedup vs baseline: 1.1834x; 1.1834x over previous
//
#include <hip/hip_runtime.h>
#include <hip/hip_fp16.h>

// ---------------------------------------------------------------------------
// 3-layer GCN + linear head.  N=50000, E=800000, D=128.
// v8 = v3 base (best: 277.9us) with:
//  * agg: 2 nodes/wave (half-wave each), 16-slot windows, 8x16B gathers per
//    lane in flight in EVERY window (v3 had 4 in the first/short window).
//    ev row via 2x uint4; header u64 issued in parallel; fold = one ^16.
//  * k_dinv dropped (v5's proven piece): fill computes dinv inline from the
//    packed wsum; agg rsqrt's its own header word.
//  * build/fill/gemm byte-identical to v3/v5's accepted forms.
// 9 dispatches: memset, build, fill, (agg,gemm)x3.
// [v2: agg is LATENCY-bound, keep 16B/lane gathers + MLP.  v4: agg+gemm
//  fusion costs occupancy/balance.  v5: batching atomics per thread hurts.
//  v6: scattered ev writes in build hurt.  v7: banked headers -> 8 lines
//  per edge in fill, 60us.  Edge-atomic pass is accepted at ~31us.]
// ---------------------------------------------------------------------------

#define D 128
#define CNT64_STRIDE 8    // one u64 counter per 64 B cache line
#define SLOTS 64          // fixed CSR capacity per node (P(deg>=64) ~ 1e-13)

typedef __attribute__((ext_vector_type(8))) _Float16 half8;
typedef __attribute__((ext_vector_type(4))) float floatx4;

// ---- MFMA GEMM body: C = A @ W (+bias), fp16 in/out, fp32 accum ----------
// 128 rows/block, 8 waves x 16 rows, v_mfma_f32_16x16x32_f16.
template <bool A_IS_F32>
__device__ __forceinline__ void gemm_body(int bid, const void* Aptr,
                                          const float* W, const float* bias,
                                          float* C32, __half* C16, int N) {
    __shared__ _Float16 Wl[128][136];
    int tid = threadIdx.x;

#pragma unroll
    for (int j = 0; j < 32; j++) {
        int e = tid + j * 512;          // 16384 elements
        Wl[e & 127][e >> 7] = (_Float16)W[e];
    }
    __syncthreads();

    int wave = tid >> 6, lane = tid & 63;
    int m = lane & 15, q = lane >> 4;
    int R0 = bid * 128 + wave * 16;

    const float*  A32p = (const float*)Aptr;
    const __half* A16p = (const __half*)Aptr;

    floatx4 acc[8];
#pragma unroll
    for (int ct = 0; ct < 8; ct++) acc[ct] = (floatx4){0.f, 0.f, 0.f, 0.f};

    int arow = R0 + m;
    bool rok = arow < N;

#pragma unroll
    for (int kk = 0; kk < 4; kk++) {
        half8 a = {0, 0, 0, 0, 0, 0, 0, 0};
        if (rok) {
            if (A_IS_F32) {
                const float* p = &A32p[(size_t)arow * 128 + kk * 32 + q * 8];
                float4 f0 = *(const float4*)p;
                float4 f1 = *(const float4*)(p + 4);
                a[0] = (_Float16)f0.x; a[1] = (_Float16)f0.y;
                a[2] = (_Float16)f0.z; a[3] = (_Float16)f0.w;
                a[4] = (_Float16)f1.x; a[5] = (_Float16)f1.y;
                a[6] = (_Float16)f1.z; a[7] = (_Float16)f1.w;
            } else {
                a = *(const half8*)&A16p[(size_t)arow * 128 + kk * 32 + q * 8];
            }
        }
#pragma unroll
        for (int ct = 0; ct < 8; ct++) {
            half8 b = *(const half8*)&Wl[ct * 16 + m][kk * 32 + q * 8];
            acc[ct] = __builtin_amdgcn_mfma_f32_16x16x32_f16(a, b, acc[ct], 0, 0, 0);
        }
    }

#pragma unroll
    for (int r = 0; r < 4; r++) {
        int row = R0 + q * 4 + r;
        if (row >= N) continue;
#pragma unroll
        for (int ct = 0; ct < 8; ct++) {
            int col = ct * 16 + m;
            float v = acc[ct][r];
            if (C16) C16[(size_t)row * 128 + col] = __float2half_rn(v);
            if (C32) C32[(size_t)row * 128 + col] = v + bias[col];
        }
    }
}

template <bool A_IS_F32>
__global__ __launch_bounds__(512) void k_gemm_mfma(const void* __restrict__ Aptr,
                                                   const float* __restrict__ W,
                                                   const float* __restrict__ bias,
                                                   float* __restrict__ C32,
                                                   __half* __restrict__ C16, int N) {
    gemm_body<A_IS_F32>(blockIdx.x, Aptr, W, bias, C32, C16, N);
}

// ---- fused: blocks [0,gg) = GEMM1 (x@W1 -> y16); [ggp,..) = edge atomics --
__global__ __launch_bounds__(512) void k_build_gemm1(const float* __restrict__ x,
                                                     const float* __restrict__ W1,
                                                     __half* __restrict__ y16,
                                                     const int* __restrict__ dst,
                                                     const float* __restrict__ w,
                                                     unsigned long long* __restrict__ cnt8,
                                                     int* __restrict__ loc,
                                                     int N, int E, int gg, int ggp) {
    int b = (int)blockIdx.x;
    if (b < gg) {
        gemm_body<true>(b, x, W1, nullptr, nullptr, y16, N);
        return;
    }
    if (b < ggp) return;
    int e = (b - ggp) * 512 + threadIdx.x;
    if (e < E) {
        int d = dst[e];
        unsigned int wq = __float2uint_rn(w[e] * 32767.0f);
        unsigned long long old =
            atomicAdd(&cnt8[(size_t)d * CNT64_STRIDE], (1ull << 32) | (unsigned long long)wq);
        loc[e] = (int)(old >> 32);
    }
}

// ---- CSR fill (fixed slots): ev[d*64+loc] = (q15(norm) << 17) | src -------
// dinv computed inline from the packed counters (low u32 = q15 wsum).
__global__ __launch_bounds__(256) void k_fill(const int* __restrict__ ei,
                                              const float* __restrict__ w,
                                              const unsigned int* __restrict__ wsum32,
                                              const int* __restrict__ loc,
                                              unsigned int* __restrict__ ev, int E) {
    int e = blockIdx.x * 256 + threadIdx.x;
    if (e < E) {
        int s = ei[e];
        int d = ei[E + e];
        float dvs = rsqrtf(1.0f + (float)wsum32[(size_t)s * 16] * (1.0f / 32767.0f));
        float dvd = rsqrtf(1.0f + (float)wsum32[(size_t)d * 16] * (1.0f / 32767.0f));
        float val = w[e] * dvs * dvd;   // in [0,1)
        unsigned int wq = __float2uint_rn(val * 32767.0f);
        ev[(size_t)d * SLOTS + loc[e]] = (wq << 17) | (unsigned int)s;
    }
}

// ---- aggregation: out_i = b + dinv_i^2*y_i + sum val*y_src ---------------
// 2 nodes per wave (h=lane>>5); within 32 lanes: g=slot-group (8 slots each),
// sl=feature slice (16B).  Every 16-slot window = 8 gathers/lane in flight.
// Epoch 0: header u64 + first-window ev (2x uint4) issued together.
__device__ __forceinline__ void fma8(float acc[8], float v, uint4 q) {
    union { uint4 uu; __half2 h2[4]; } U; U.uu = q;
    float2 f0 = __half22float2(U.h2[0]);
    float2 f1 = __half22float2(U.h2[1]);
    float2 f2 = __half22float2(U.h2[2]);
    float2 f3 = __half22float2(U.h2[3]);
    acc[0] = fmaf(v, f0.x, acc[0]); acc[1] = fmaf(v, f0.y, acc[1]);
    acc[2] = fmaf(v, f1.x, acc[2]); acc[3] = fmaf(v, f1.y, acc[3]);
    acc[4] = fmaf(v, f2.x, acc[4]); acc[5] = fmaf(v, f2.y, acc[5]);
    acc[6] = fmaf(v, f3.x, acc[6]); acc[7] = fmaf(v, f3.y, acc[7]);
}

__global__ __launch_bounds__(256) void k_agg(const __half* __restrict__ y16,
                                             const unsigned long long* __restrict__ cnt8,
                                             const unsigned int* __restrict__ ev,
                                             const float* __restrict__ bias,
                                             __half* __restrict__ out16,
                                             int N, int relu) {
    int wave = threadIdx.x >> 6;
    int lane = threadIdx.x & 63;
    int h  = lane >> 5;          // node within wave
    int r5 = lane & 31;
    int g  = r5 >> 4;            // slot group: slots base+g*8 .. base+g*8+7
    int sl = r5 & 15;            // feature slice: 8 fp16 at sl*8

    int i = blockIdx.x * 8 + wave * 2 + h;
    if (i >= N) return;

    const unsigned int* evp = ev + (size_t)i * SLOTS;

    // ---- epoch 0: header + first-window ev, all in flight ----------------
    unsigned long long pk = cnt8[(size_t)i * CNT64_STRIDE];
    uint4 ea = *(const uint4*)&evp[g * 8];
    uint4 eb = *(const uint4*)&evp[g * 8 + 4];

    int cnt = min((int)(pk >> 32), SLOTS);
    float di = rsqrtf(1.0f + (float)(unsigned int)pk * (1.0f / 32767.0f));

    float acc[8];
#pragma unroll
    for (int j = 0; j < 8; j++) acc[j] = 0.f;

    // ---- window 0 (slots 0..15): 8 gathers/lane --------------------------
    {
        unsigned int p[8] = {ea.x, ea.y, ea.z, ea.w, eb.x, eb.y, eb.z, eb.w};
        float v[8]; uint4 q4[8];
#pragma unroll
        for (int u = 0; u < 8; u++) {
            bool ok = (g * 8 + u) < cnt;
            v[u] = ok ? (float)(p[u] >> 17) * (1.0f / 32767.0f) : 0.0f;
            int s = min((int)(p[u] & 0x1FFFFu), N - 1);   // clamp: may be garbage
            q4[u] = *(const uint4*)&y16[(size_t)s * D + sl * 8];
        }
#pragma unroll
        for (int u = 0; u < 8; u++) fma8(acc, v[u], q4[u]);
    }

    // ---- tail windows (16 slots each, 8 gathers/lane) --------------------
    for (int base = 16; base < cnt; base += 16) {
        uint4 ta = *(const uint4*)&evp[base + g * 8];       // row always 64 words
        uint4 tb = *(const uint4*)&evp[base + g * 8 + 4];
        unsigned int p[8] = {ta.x, ta.y, ta.z, ta.w, tb.x, tb.y, tb.z, tb.w};
        float v[8]; uint4 q4[8];
#pragma unroll
        for (int u = 0; u < 8; u++) {
            bool ok = (base + g * 8 + u) < cnt;
            v[u] = ok ? (float)(p[u] >> 17) * (1.0f / 32767.0f) : 0.0f;
            int s = min((int)(p[u] & 0x1FFFFu), N - 1);
            q4[u] = *(const uint4*)&y16[(size_t)s * D + sl * 8];
        }
#pragma unroll
        for (int u = 0; u < 8; u++) fma8(acc, v[u], q4[u]);
    }

    // fold the 2 slot-groups (lane ^16, within each 32-lane node half)
#pragma unroll
    for (int j = 0; j < 8; j++) acc[j] += __shfl_xor(acc[j], 16, 64);

    if (g == 0) {
        float di2 = di * di;
        union { uint4 u; __half2 h2[4]; } S;
        S.u = *(const uint4*)&y16[(size_t)i * D + sl * 8];
        float2 s0 = __half22float2(S.h2[0]);
        float2 s1 = __half22float2(S.h2[1]);
        float2 s2 = __half22float2(S.h2[2]);
        float2 s3 = __half22float2(S.h2[3]);
        float4 b0 = *(const float4*)&bias[sl * 8];
        float4 b1 = *(const float4*)&bias[sl * 8 + 4];
        float o[8];
        o[0] = b0.x + acc[0] + di2 * s0.x;
        o[1] = b0.y + acc[1] + di2 * s0.y;
        o[2] = b0.z + acc[2] + di2 * s1.x;
        o[3] = b0.w + acc[3] + di2 * s1.y;
        o[4] = b1.x + acc[4] + di2 * s2.x;
        o[5] = b1.y + acc[5] + di2 * s2.y;
        o[6] = b1.z + acc[6] + di2 * s3.x;
        o[7] = b1.w + acc[7] + di2 * s3.y;
        if (relu) {
#pragma unroll
            for (int j = 0; j < 8; j++) o[j] = fmaxf(o[j], 0.f);
        }
        union { uint4 u; __half2 h2[4]; } O;
        O.h2[0] = __float22half2_rn(make_float2(o[0], o[1]));
        O.h2[1] = __float22half2_rn(make_float2(o[2], o[3]));
        O.h2[2] = __float22half2_rn(make_float2(o[4], o[5]));
        O.h2[3] = __float22half2_rn(make_float2(o[6], o[7]));
        *(uint4*)&out16[(size_t)i * D + sl * 8] = O.u;
    }
}

// ---------------------------------------------------------------------------
extern "C" void kernel_launch(void* const* d_in, const int* in_sizes, int n_in,
                              void* d_out, int out_size, void* d_ws, size_t ws_size,
                              hipStream_t stream) {
    const float* x  = (const float*)d_in[0];
    const int*   ei = (const int*)d_in[1];     // [2,E]: src row then dst row
    const float* ew = (const float*)d_in[2];
    const float* W1 = (const float*)d_in[3];
    const float* b1 = (const float*)d_in[4];
    const float* W2 = (const float*)d_in[5];
    const float* b2 = (const float*)d_in[6];
    const float* W3 = (const float*)d_in[7];
    const float* b3 = (const float*)d_in[8];
    const float* Wl = (const float*)d_in[9];
    const float* bl = (const float*)d_in[10];

    int N = in_sizes[0] / D;    // 50000
    int E = in_sizes[2];        // 800000

    char* ws = (char*)d_ws;
    size_t off = 0;
    auto alloc = [&](size_t bytes) {
        void* p = ws + off;
        off = (off + bytes + 255) & ~(size_t)255;
        return p;
    };
    unsigned long long* cnt8 = (unsigned long long*)alloc((size_t)N * 64); // padded
    int*    loc  = (int*)alloc((size_t)E * 4);
    unsigned int* ev = (unsigned int*)alloc((size_t)N * SLOTS * 4);  // 12.8MB
    __half* yA   = (__half*)alloc((size_t)N * D * 2);   // row-major [N][128]
    __half* yB   = (__half*)alloc((size_t)N * D * 2);   // row-major [N][128]

    int nbE    = (E + 255) / 256;      // 3125 (fill)
    int nbE512 = (E + 511) / 512;      // 1563 (build edge part)
    int gg     = (N + 127) / 128;      // 391 GEMM blocks
    int ggp    = (gg + 7) & ~7;        // 392
    int ga     = (N + 7) / 8;          // 6250 agg blocks (4 waves, 8 nodes)

    hipMemsetAsync(cnt8, 0, (size_t)N * 64, stream);
    k_build_gemm1<<<ggp + nbE512, 512, 0, stream>>>(x, W1, yA, ei + E, ew,
                                                    cnt8, loc, N, E, gg, ggp);
    k_fill<<<nbE, 256, 0, stream>>>(ei, ew, (const unsigned int*)cnt8, loc, ev, E);

    k_agg<<<ga, 256, 0, stream>>>(yA, cnt8, ev, b1, yB, N, 1);
    k_gemm_mfma<false><<<gg, 512, 0, stream>>>(yB, W2, nullptr, nullptr, yA, N);
    k_agg<<<ga, 256, 0, stream>>>(yA, cnt8, ev, b2, yB, N, 1);
    k_gemm_mfma<false><<<gg, 512, 0, stream>>>(yB, W3, nullptr, nullptr, yA, N);
    k_agg<<<ga, 256, 0, stream>>>(yA, cnt8, ev, b3, yB, N, 0);
    k_gemm_mfma<false><<<gg, 512, 0, stream>>>(yB, Wl, bl, (float*)d_out, nullptr, N);
}